// Round 1
// baseline (338.789 us; speedup 1.0000x reference)
//
#include <hip/hip_runtime.h>
#include <hip/hip_bf16.h>
#include <stdint.h>

typedef __bf16 bf16x8 __attribute__((ext_vector_type(8)));
typedef float  f32x4  __attribute__((ext_vector_type(4)));

#define RATIO 0.08838834764831845f
#define EPSV  1e-4f

#define GLOBAL_AS __attribute__((address_space(1)))
#define LDS_AS    __attribute__((address_space(3)))

static __device__ __forceinline__ void gload16(const void* g, void* l) {
  __builtin_amdgcn_global_load_lds((GLOBAL_AS const void*)g, (LDS_AS void*)l, 16, 0, 0);
}

// ---------------- workspace layout (bytes) ----------------
static constexpr size_t OFF_XB    = 0;                        // 16384*128*2
static constexpr size_t OFF_WCAT  = OFF_XB    + 4194304;      // 384*128*2
static constexpr size_t OFF_MQ    = OFF_WCAT  + 98304;        // 1024*128*2
static constexpr size_t OFF_MK    = OFF_MQ    + 262144;
static constexpr size_t OFF_BCAT  = OFF_MK    + 262144;       // 384*4 (pad)
static constexpr size_t OFF_BQF   = OFF_BCAT  + 2048;         // 1024*4
static constexpr size_t OFF_BKF   = OFF_BQF   + 4096;
static constexpr size_t OFF_Y     = OFF_BKF   + 4096;         // 16384*384*4
static constexpr size_t OFF_QF    = OFF_Y     + 25165824;     // 8*2048*1024*2
static constexpr size_t OFF_KF    = OFF_QF    + 33554432;
static constexpr size_t OFF_KFT   = OFF_KF    + 33554432;
static constexpr size_t OFF_VFT   = OFF_KFT   + 33554432;     // 8*128*2048*2
static constexpr size_t OFF_KPART = OFF_VFT   + 4194304;      // 8*128*4
static constexpr size_t OFF_KMAX  = OFF_KPART + 4096;         // 64*4
static constexpr size_t OFF_KSUM  = OFF_KMAX  + 256;          // 8*1024*4
static constexpr size_t OFF_DINV  = OFF_KSUM  + 32768;        // 16384*4
static constexpr size_t OFF_CTXP  = OFF_DINV  + 65536;        // 4*8*128*1024*4
static constexpr size_t OFF_CTXT  = OFF_CTXP  + 16777216;     // 8*128*1024*2
static constexpr size_t WS_NEED   = OFF_CTXT  + 2097152;      // ~147 MiB

// ---------------- shared NT-GEMM core: C(128x128) = A(tm:,*) * B(tn:,*)^T ----
static __device__ __forceinline__ void gemm_core(
    const __hip_bfloat16* __restrict__ A, const __hip_bfloat16* __restrict__ B,
    int lda, int ldb, int K, int tm, int tn,
    __bf16* As, __bf16* Bs, f32x4 acc[4][4]) {
  const int t    = threadIdx.x;
  const int w    = t >> 6;
  const int lane = t & 63;
  const int m_off = (w >> 1) << 6;
  const int n_off = (w & 1) << 6;
  const int r0 = t >> 2;            // 0..63 staging row
  const int kk = (t & 3) << 3;      // 0,8,16,24
  char* Asb = (char*)As + (w << 10);
  char* Bsb = (char*)Bs + (w << 10);
  const int frow = lane & 15;
  const int koff = (lane >> 4) << 3;
  for (int k0 = 0; k0 < K; k0 += 32) {
    const __hip_bfloat16* Ag = A + (size_t)(tm + r0) * lda + (k0 + kk);
    const __hip_bfloat16* Bg = B + (size_t)(tn + r0) * ldb + (k0 + kk);
    gload16(Ag, Asb);
    gload16(Ag + (size_t)64 * lda, Asb + 4096);
    gload16(Bg, Bsb);
    gload16(Bg + (size_t)64 * ldb, Bsb + 4096);
    __syncthreads();
    bf16x8 af[4], bfr[4];
#pragma unroll
    for (int mi = 0; mi < 4; ++mi)
      af[mi] = *(const bf16x8*)(As + ((m_off + mi * 16 + frow) << 5) + koff);
#pragma unroll
    for (int ni = 0; ni < 4; ++ni)
      bfr[ni] = *(const bf16x8*)(Bs + ((n_off + ni * 16 + frow) << 5) + koff);
#pragma unroll
    for (int mi = 0; mi < 4; ++mi)
#pragma unroll
      for (int ni = 0; ni < 4; ++ni)
        acc[mi][ni] = __builtin_amdgcn_mfma_f32_16x16x32_bf16(af[mi], bfr[ni], acc[mi][ni], 0, 0, 0);
    __syncthreads();
  }
}

#define ZERO_ACC(acc) do {                                   \
  _Pragma("unroll") for (int a_ = 0; a_ < 4; ++a_)           \
  _Pragma("unroll") for (int b_ = 0; b_ < 4; ++b_)           \
    acc[a_][b_] = (f32x4){0.f, 0.f, 0.f, 0.f};               \
} while (0)

// ---------------- prep kernels ----------------
__global__ void k_prepwb(const float* __restrict__ Wq, const float* __restrict__ bq,
                         const float* __restrict__ Wk, const float* __restrict__ bk,
                         const float* __restrict__ Wv, const float* __restrict__ bv,
                         __hip_bfloat16* __restrict__ Wcat, float* __restrict__ bcat) {
  int i = blockIdx.x * 256 + threadIdx.x;
  if (i < 49152) {
    int mat = i >> 14, rem = i & 16383;
    const float* W = (mat == 0) ? Wq : ((mat == 1) ? Wk : Wv);
    Wcat[i] = __float2bfloat16(W[rem]);
  }
  if (i < 384) {
    int mat = i >> 7;
    const float* b = (mat == 0) ? bq : ((mat == 1) ? bk : bv);
    bcat[i] = b[i & 127];
  }
}

__global__ void k_prepM(const float* __restrict__ Wq, const float* __restrict__ bq,
                        const float* __restrict__ Wk, const float* __restrict__ bk,
                        const float* __restrict__ proj,
                        __hip_bfloat16* __restrict__ Mq, __hip_bfloat16* __restrict__ Mk,
                        float* __restrict__ bqf, float* __restrict__ bkf) {
  int i = blockIdx.x * 256 + threadIdx.x;
  if (i < 262144) {
    int which = i >> 17;
    int rem = i & 131071;
    int hj = rem >> 7, e = rem & 127;
    int hh = hj >> 7, j = hj & 127;
    const float* W = which ? Wk : Wq;
    float s = 0.f;
#pragma unroll
    for (int u = 0; u < 16; ++u) s += proj[j * 16 + u] * W[(hh * 16 + u) * 128 + e];
    if (which) Mk[rem] = __float2bfloat16(0.5f * s);
    else       Mq[rem] = __float2bfloat16(0.5f * s);
  }
  if (i < 2048) {
    int which = i >> 10;
    int hj = i & 1023, hh = hj >> 7, j = hj & 127;
    const float* b = which ? bk : bq;
    float s = 0.f;
#pragma unroll
    for (int u = 0; u < 16; ++u) s += proj[j * 16 + u] * b[hh * 16 + u];
    if (which) bkf[hj] = 0.5f * s;
    else       bqf[hj] = 0.5f * s;
  }
}

__global__ void k_convx(const float* __restrict__ x, __hip_bfloat16* __restrict__ xb) {
  int i = (blockIdx.x * 256 + threadIdx.x) * 4;
  f32x4 v = *(const f32x4*)(x + i);
#pragma unroll
  for (int j = 0; j < 4; ++j) xb[i + j] = __float2bfloat16(v[j]);
}

// ---------------- projection GEMM: Y = x*Wcat^T + bcat ----------------
__global__ __launch_bounds__(256) void k_proj(
    const __hip_bfloat16* __restrict__ xb, const __hip_bfloat16* __restrict__ Wcat,
    const float* __restrict__ bcat, float* __restrict__ Y) {
  __shared__ __align__(16) __bf16 As[4096], Bs[4096];
  const int tm = blockIdx.x << 7, tn = blockIdx.y << 7;
  f32x4 acc[4][4];
  ZERO_ACC(acc);
  gemm_core(xb, Wcat, 128, 128, 128, tm, tn, As, Bs, acc);
  const int t = threadIdx.x, w = t >> 6, lane = t & 63;
  const int m_off = (w >> 1) << 6, n_off = (w & 1) << 6;
#pragma unroll
  for (int ni = 0; ni < 4; ++ni) {
    const int col = tn + n_off + ni * 16 + (lane & 15);
    const float bias = bcat[col];
#pragma unroll
    for (int mi = 0; mi < 4; ++mi)
#pragma unroll
      for (int i = 0; i < 4; ++i) {
        const int row = tm + m_off + mi * 16 + ((lane >> 4) << 2) + i;
        Y[(size_t)row * 384 + col] = acc[mi][ni][i] + bias;
      }
  }
}

// ---------------- vfT build: vfT[h][r*16+t][c] = Y[r*2048+c][256+h*16+t] -----
__global__ void k_vft(const float* __restrict__ Y, __hip_bfloat16* __restrict__ vfT) {
  const int h = blockIdx.x, r = blockIdx.y;
  __shared__ float tile[16][17];
  const int a = threadIdx.x & 15, b = threadIdx.x >> 4;
  for (int c0 = 0; c0 < 2048; c0 += 16) {
    tile[b][a] = Y[(size_t)(r * 2048 + c0 + b) * 384 + 256 + h * 16 + a];
    __syncthreads();
    vfT[((size_t)(h * 128 + r * 16 + b)) * 2048 + c0 + a] = __float2bfloat16(tile[a][b]);
    __syncthreads();
  }
}

// ---------------- q features ----------------
__global__ __launch_bounds__(256) void k_dashq(
    const __hip_bfloat16* __restrict__ xb, const __hip_bfloat16* __restrict__ Mq,
    const float* __restrict__ bqf, const float* __restrict__ Y,
    __hip_bfloat16* __restrict__ qf) {
  __shared__ __align__(16) __bf16 As[4096], Bs[4096];
  __shared__ float diag_s[128];
  __shared__ float rmax_s[2][128];
  const int h = blockIdx.y;
  const int tm = blockIdx.x << 7;
  f32x4 acc[4][4];
  ZERO_ACC(acc);
  gemm_core(xb, Mq + h * 16384, 128, 128, 128, tm, 0, As, Bs, acc);
  const int t = threadIdx.x, w = t >> 6, lane = t & 63;
  const int m_off = (w >> 1) << 6, n_off = (w & 1) << 6;
  if (t < 128) {
    const float* yp = Y + (size_t)(tm + t) * 384 + h * 16;
    float s = 0.f;
#pragma unroll
    for (int u = 0; u < 16; ++u) s += yp[u] * yp[u];
    diag_s[t] = 0.125f * s;
  }
  float bia[4];
#pragma unroll
  for (int ni = 0; ni < 4; ++ni) bia[ni] = bqf[h * 128 + n_off + ni * 16 + (lane & 15)];
  float rmx[4][4];
#pragma unroll
  for (int mi = 0; mi < 4; ++mi)
#pragma unroll
    for (int i = 0; i < 4; ++i) {
      float m0 = acc[mi][0][i] + bia[0];
      m0 = fmaxf(m0, acc[mi][1][i] + bia[1]);
      m0 = fmaxf(m0, acc[mi][2][i] + bia[2]);
      m0 = fmaxf(m0, acc[mi][3][i] + bia[3]);
      rmx[mi][i] = m0;
    }
#pragma unroll
  for (int off = 1; off < 16; off <<= 1)
#pragma unroll
    for (int mi = 0; mi < 4; ++mi)
#pragma unroll
      for (int i = 0; i < 4; ++i)
        rmx[mi][i] = fmaxf(rmx[mi][i], __shfl_xor(rmx[mi][i], off));
  if ((lane & 15) == 0) {
#pragma unroll
    for (int mi = 0; mi < 4; ++mi)
#pragma unroll
      for (int i = 0; i < 4; ++i)
        rmax_s[w & 1][m_off + mi * 16 + ((lane >> 4) << 2) + i] = rmx[mi][i];
  }
  __syncthreads();
#pragma unroll
  for (int mi = 0; mi < 4; ++mi) {
#pragma unroll
    for (int i = 0; i < 4; ++i) {
      const int rl = m_off + mi * 16 + ((lane >> 4) << 2) + i;
      const int rg = tm + rl;
      const int c = rg & 2047, r = rg >> 11;
      const float md = diag_s[rl] + fmaxf(rmax_s[0][rl], rmax_s[1][rl]);
#pragma unroll
      for (int ni = 0; ni < 4; ++ni) {
        const int j = n_off + ni * 16 + (lane & 15);
        const float f = RATIO * (__expf(acc[mi][ni][i] + bia[ni] - md) + EPSV);
        qf[((size_t)((h << 11) + c) << 10) + (r << 7) + j] = __float2bfloat16(f);
      }
    }
  }
}

// ---------------- k features: pass A (max) ----------------
__global__ __launch_bounds__(256) void k_dashk_max(
    const __hip_bfloat16* __restrict__ xb, const __hip_bfloat16* __restrict__ Mk,
    const float* __restrict__ bkf, float* __restrict__ kpart) {
  __shared__ __align__(16) __bf16 As[4096], Bs[4096];
  __shared__ float wmax[4];
  const int h = blockIdx.y;
  const int tm = blockIdx.x << 7;
  f32x4 acc[4][4];
  ZERO_ACC(acc);
  gemm_core(xb, Mk + h * 16384, 128, 128, 128, tm, 0, As, Bs, acc);
  const int t = threadIdx.x, w = t >> 6, lane = t & 63;
  const int n_off = (w & 1) << 6;
  float mx = -1e30f;
#pragma unroll
  for (int ni = 0; ni < 4; ++ni) {
    const float bia = bkf[h * 128 + n_off + ni * 16 + (lane & 15)];
#pragma unroll
    for (int mi = 0; mi < 4; ++mi)
#pragma unroll
      for (int i = 0; i < 4; ++i) mx = fmaxf(mx, acc[mi][ni][i] + bia);
  }
#pragma unroll
  for (int off = 1; off < 64; off <<= 1) mx = fmaxf(mx, __shfl_xor(mx, off));
  if (lane == 0) wmax[w] = mx;
  __syncthreads();
  if (t == 0) kpart[h * 128 + blockIdx.x] = fmaxf(fmaxf(wmax[0], wmax[1]), fmaxf(wmax[2], wmax[3]));
}

__global__ void k_kmaxred(const float* __restrict__ kpart, float* __restrict__ kmax) {
  const int t = threadIdx.x;  // 64
  const int r = t >> 3, h = t & 7;
  float m = -1e30f;
  for (int i = 0; i < 16; ++i) m = fmaxf(m, kpart[h * 128 + r * 16 + i]);
  kmax[r * 8 + h] = m;
}

// ---------------- k features: pass B (features, kf + kfT) ----------------
__global__ __launch_bounds__(256) void k_dashk_feat(
    const __hip_bfloat16* __restrict__ xb, const __hip_bfloat16* __restrict__ Mk,
    const float* __restrict__ bkf, const float* __restrict__ Y,
    const float* __restrict__ kmax,
    __hip_bfloat16* __restrict__ kf, __hip_bfloat16* __restrict__ kfT) {
  __shared__ __align__(16) __bf16 As[4096], Bs[4096];
  __shared__ float diag_s[128];
  __shared__ __align__(16) __bf16 kT[128 * 136];
  const int h = blockIdx.y;
  const int tm = blockIdx.x << 7;
  f32x4 acc[4][4];
  ZERO_ACC(acc);
  gemm_core(xb, Mk + h * 16384, 128, 128, 128, tm, 0, As, Bs, acc);
  const int t = threadIdx.x, w = t >> 6, lane = t & 63;
  const int m_off = (w >> 1) << 6, n_off = (w & 1) << 6;
  if (t < 128) {
    const float* yp = Y + (size_t)(tm + t) * 384 + 128 + h * 16;
    float s = 0.f;
#pragma unroll
    for (int u = 0; u < 16; ++u) s += yp[u] * yp[u];
    diag_s[t] = 0.125f * s;
  }
  const int r = tm >> 11;
  const int c0 = tm & 2047;
  const float m = kmax[r * 8 + h];
  float bia[4];
#pragma unroll
  for (int ni = 0; ni < 4; ++ni) bia[ni] = bkf[h * 128 + n_off + ni * 16 + (lane & 15)];
  __syncthreads();
#pragma unroll
  for (int mi = 0; mi < 4; ++mi) {
#pragma unroll
    for (int i = 0; i < 4; ++i) {
      const int rl = m_off + mi * 16 + ((lane >> 4) << 2) + i;
      const int c = c0 + rl;
      const float dm = diag_s[rl] + m;
#pragma unroll
      for (int ni = 0; ni < 4; ++ni) {
        const int j = n_off + ni * 16 + (lane & 15);
        const float f = RATIO * (__expf(acc[mi][ni][i] + bia[ni] - dm) + EPSV);
        kf[((size_t)((h << 11) + c) << 10) + (r << 7) + j] = __float2bfloat16(f);
        kT[j * 136 + rl] = (__bf16)f;
      }
    }
  }
  __syncthreads();
  const int j2 = t >> 1, half = t & 1;
  __bf16* dst = (__bf16*)kfT + (((size_t)(h << 10) + (r << 7) + j2) << 11) + c0 + (half << 6);
  const __bf16* srcr = kT + j2 * 136 + (half << 6);
#pragma unroll
  for (int q8 = 0; q8 < 8; ++q8)
    *(bf16x8*)(dst + (q8 << 3)) = *(const bf16x8*)(srcr + (q8 << 3));
}

// ---------------- k_sum / D_inv ----------------
__global__ void k_ksum(const __hip_bfloat16* __restrict__ kf, float* __restrict__ ksum) {
  const int h = blockIdx.y, d = blockIdx.x * 128 + threadIdx.x;
  const __hip_bfloat16* p = kf + ((size_t)h << 21) + d;
  float s = 0.f;
  for (int c = 0; c < 2048; ++c) s += __bfloat162float(p[(size_t)c << 10]);
  ksum[h * 1024 + d] = s;
}

__global__ __launch_bounds__(256) void k_dinv(
    const __hip_bfloat16* __restrict__ qf, const float* __restrict__ ksum,
    float* __restrict__ dinv) {
  const int t = threadIdx.x, w = t >> 6, lane = t & 63;
  const int h = blockIdx.y;
  const int c = blockIdx.x * 4 + w;
  const __bf16* qp = (const __bf16*)qf + ((size_t)((h << 11) + c) << 10);
  const float* ks = ksum + h * 1024;
  const int d0 = lane << 4;
  bf16x8 v0 = *(const bf16x8*)(qp + d0);
  bf16x8 v1 = *(const bf16x8*)(qp + d0 + 8);
  float s = 0.f;
#pragma unroll
  for (int j = 0; j < 8; ++j) s += (float)v0[j] * ks[d0 + j] + (float)v1[j] * ks[d0 + 8 + j];
#pragma unroll
  for (int off = 1; off < 64; off <<= 1) s += __shfl_xor(s, off);
  if (lane == 0) dinv[(h << 11) + c] = 1.0f / s;
}

// ---------------- attn GEMM ----------------
__global__ __launch_bounds__(256) void k_attn(
    const __hip_bfloat16* __restrict__ qf, const __hip_bfloat16* __restrict__ kf,
    float* __restrict__ attn) {
  __shared__ __align__(16) __bf16 As[4096], Bs[4096];
  const int h = blockIdx.z;
  const int tm = blockIdx.x << 7, tn = blockIdx.y << 7;
  f32x4 acc[4][4];
  ZERO_ACC(acc);
  gemm_core(qf + ((size_t)h << 21), kf + ((size_t)h << 21), 1024, 1024, 1024, tm, tn, As, Bs, acc);
  float* Cc = attn + ((size_t)h << 22);
  const int t = threadIdx.x, w = t >> 6, lane = t & 63;
  const int m_off = (w >> 1) << 6, n_off = (w & 1) << 6;
#pragma unroll
  for (int mi = 0; mi < 4; ++mi)
#pragma unroll
    for (int i = 0; i < 4; ++i) {
      const int row = tm + m_off + mi * 16 + ((lane >> 4) << 2) + i;
#pragma unroll
      for (int ni = 0; ni < 4; ++ni) {
        const int col = tn + n_off + ni * 16 + (lane & 15);
        Cc[((size_t)row << 11) + col] = acc[mi][ni][i];
      }
    }
}

// ---------------- context GEMM (K-split) ----------------
__global__ __launch_bounds__(256) void k_ctx(
    const __hip_bfloat16* __restrict__ vfT, const __hip_bfloat16* __restrict__ kfT,
    float* __restrict__ ctxp) {
  __shared__ __align__(16) __bf16 As[4096], Bs[4096];
  const int z = blockIdx.z, h = z >> 2, kc = z & 3;
  const int tn = blockIdx.y << 7;
  f32x4 acc[4][4];
  ZERO_ACC(acc);
  gemm_core(vfT + ((size_t)h << 18) + (kc << 9), kfT + ((size_t)h << 21) + (kc << 9),
            2048, 2048, 512, 0, tn, As, Bs, acc);
  float* Cp = ctxp + ((size_t)(kc * 8 + h) << 17);
  const int t = threadIdx.x, w = t >> 6, lane = t & 63;
  const int m_off = (w >> 1) << 6, n_off = (w & 1) << 6;
#pragma unroll
  for (int mi = 0; mi < 4; ++mi)
#pragma unroll
    for (int i = 0; i < 4; ++i) {
      const int row = m_off + mi * 16 + ((lane >> 4) << 2) + i;
#pragma unroll
      for (int ni = 0; ni < 4; ++ni) {
        const int col = tn + n_off + ni * 16 + (lane & 15);
        Cp[((size_t)row << 10) + col] = acc[mi][ni][i];
      }
    }
}

__global__ void k_ctxred(const float* __restrict__ ctxp, __hip_bfloat16* __restrict__ ctxT) {
  const int i = blockIdx.x * 256 + threadIdx.x;
  const float s = ctxp[i] + ctxp[i + 1048576] + ctxp[i + 2097152] + ctxp[i + 3145728];
  ctxT[i] = __float2bfloat16(s);
}

// ---------------- out GEMM + D_inv scale + scatter ----------------
__global__ __launch_bounds__(256) void k_out(
    const __hip_bfloat16* __restrict__ qf, const __hip_bfloat16* __restrict__ ctxT,
    const float* __restrict__ dinv, float* __restrict__ outp) {
  __shared__ __align__(16) __bf16 As[4096], Bs[4096];
  const int h = blockIdx.z;
  const int tm = blockIdx.x << 7;
  f32x4 acc[4][4];
  ZERO_ACC(acc);
  gemm_core(qf + ((size_t)h << 21), ctxT + ((size_t)h << 17), 1024, 1024, 1024, tm, 0, As, Bs, acc);
  const int t = threadIdx.x, w = t >> 6, lane = t & 63;
  const int m_off = (w >> 1) << 6, n_off = (w & 1) << 6;
#pragma unroll
  for (int mi = 0; mi < 4; ++mi)
#pragma unroll
    for (int i = 0; i < 4; ++i) {
      const int row = tm + m_off + mi * 16 + ((lane >> 4) << 2) + i;
      const float dv = dinv[(h << 11) + row];
#pragma unroll
      for (int ni = 0; ni < 4; ++ni) {
        const int col = n_off + ni * 16 + (lane & 15);
        const int rb = col >> 4, tt = col & 15;
        outp[(((size_t)(rb << 11) + row) << 7) + (h << 4) + tt] = acc[mi][ni][i] * dv;
      }
    }
}

// ---------------- launch ----------------
extern "C" void kernel_launch(void* const* d_in, const int* in_sizes, int n_in,
                              void* d_out, int out_size, void* d_ws, size_t ws_size,
                              hipStream_t stream) {
  const float* x    = (const float*)d_in[0];
  const float* Wq   = (const float*)d_in[1];
  const float* bq   = (const float*)d_in[2];
  const float* Wk   = (const float*)d_in[3];
  const float* bk   = (const float*)d_in[4];
  const float* Wv   = (const float*)d_in[5];
  const float* bv   = (const float*)d_in[6];
  const float* proj = (const float*)d_in[7];
  if (ws_size < WS_NEED) return;

  char* ws = (char*)d_ws;
  __hip_bfloat16* xb   = (__hip_bfloat16*)(ws + OFF_XB);
  __hip_bfloat16* Wcat = (__hip_bfloat16*)(ws + OFF_WCAT);
  __hip_bfloat16* Mq   = (__hip_bfloat16*)(ws + OFF_MQ);
  __hip_bfloat16* Mk   = (__hip_bfloat16*)(ws + OFF_MK);
  float* bcat = (float*)(ws + OFF_BCAT);
  float* bqf  = (float*)(ws + OFF_BQF);
  float* bkf  = (float*)(ws + OFF_BKF);
  float* Y    = (float*)(ws + OFF_Y);
  __hip_bfloat16* qf  = (__hip_bfloat16*)(ws + OFF_QF);
  __hip_bfloat16* kf  = (__hip_bfloat16*)(ws + OFF_KF);
  __hip_bfloat16* kfT = (__hip_bfloat16*)(ws + OFF_KFT);
  __hip_bfloat16* vfT = (__hip_bfloat16*)(ws + OFF_VFT);
  float* kpart = (float*)(ws + OFF_KPART);
  float* kmax  = (float*)(ws + OFF_KMAX);
  float* ksum  = (float*)(ws + OFF_KSUM);
  float* dinv  = (float*)(ws + OFF_DINV);
  float* ctxp  = (float*)(ws + OFF_CTXP);
  __hip_bfloat16* ctxT = (__hip_bfloat16*)(ws + OFF_CTXT);

  float* outp = (float*)d_out;
  float* attn = (float*)d_out + 2097152;

  k_prepwb<<<dim3(192), dim3(256), 0, stream>>>(Wq, bq, Wk, bk, Wv, bv, Wcat, bcat);
  k_prepM<<<dim3(1024), dim3(256), 0, stream>>>(Wq, bq, Wk, bk, proj, Mq, Mk, bqf, bkf);
  k_convx<<<dim3(2048), dim3(256), 0, stream>>>(x, xb);
  k_proj<<<dim3(128, 3), dim3(256), 0, stream>>>(xb, Wcat, bcat, Y);
  k_vft<<<dim3(8, 8), dim3(256), 0, stream>>>(Y, vfT);
  k_dashq<<<dim3(128, 8), dim3(256), 0, stream>>>(xb, Mq, bqf, Y, qf);
  k_dashk_max<<<dim3(128, 8), dim3(256), 0, stream>>>(xb, Mk, bkf, kpart);
  k_kmaxred<<<dim3(1), dim3(64), 0, stream>>>(kpart, kmax);
  k_dashk_feat<<<dim3(128, 8), dim3(256), 0, stream>>>(xb, Mk, bkf, Y, kmax, kf, kfT);
  k_ksum<<<dim3(8, 8), dim3(128), 0, stream>>>(kf, ksum);
  k_dinv<<<dim3(512, 8), dim3(256), 0, stream>>>(qf, ksum, dinv);
  k_attn<<<dim3(16, 16, 8), dim3(256), 0, stream>>>(qf, kf, attn);
  k_ctx<<<dim3(1, 8, 32), dim3(256), 0, stream>>>(vfT, kfT, ctxp);
  k_ctxred<<<dim3(4096), dim3(256), 0, stream>>>(ctxp, ctxT);
  k_out<<<dim3(16, 1, 8), dim3(256), 0, stream>>>(qf, ctxT, dinv, outp);
}